// Round 2
// baseline (209.664 us; speedup 1.0000x reference)
//
#include <hip/hip_runtime.h>

#define B_ 4
#define T_ 2048
#define C_ 1024
#define H_ 64
#define M_ (B_*T_)

typedef __bf16 bf16x8 __attribute__((ext_vector_type(8)));
typedef float f32x4 __attribute__((ext_vector_type(4)));
typedef short short8 __attribute__((ext_vector_type(8)));
typedef short short4v __attribute__((ext_vector_type(4)));
typedef float float4v __attribute__((ext_vector_type(4)));

static __device__ __forceinline__ unsigned short f2bf(float f) {
    union { float f; unsigned u; } x; x.f = f;
    unsigned r = x.u + 0x7fffu + ((x.u >> 16) & 1u);
    return (unsigned short)(r >> 16);
}

static __device__ __forceinline__ f32x4 mfma16(bf16x8 a, bf16x8 b, f32x4 c) {
    return __builtin_amdgcn_mfma_f32_16x16x32_bf16(a, b, c, 0, 0, 0);
}

// ---------------------------------------------------------------------------
// Kernel 1: repack Wk|Wq|Wv (fp32 [1024][64]) into bf16 MFMA B-fragment order.
// Wtf layout: frag f = kk*12 + n (kk: K-step 0..31, n: out-col tile 0..11),
// within frag: lane l (0..63) holds 8 elems: W[k = kk*32+(l>>4)*8+j][col n*16+(l&15)]
// n 0..3 -> Wk cols 0..63 ; 4..7 -> Wq (pre-scaled by 1/32) ; 8..11 -> Wv
// ---------------------------------------------------------------------------
__global__ __launch_bounds__(256) void wconv_kernel(const float* __restrict__ Wk,
                                                    const float* __restrict__ Wq,
                                                    const float* __restrict__ Wv,
                                                    unsigned short* __restrict__ Wtf) {
    int t = blockIdx.x * 256 + threadIdx.x;   // 0..24575
    int f = t >> 6;                           // frag 0..383
    int l = t & 63;
    int n = f % 12, kk = f / 12;
    int sel = n >> 2;
    int wcol = (n & 3) * 16 + (l & 15);
    int kbase = kk * 32 + (l >> 4) * 8;
    const float* W = (sel == 0) ? Wk : ((sel == 1) ? Wq : Wv);
    float scale = (sel == 1) ? 0.03125f : 1.0f;
    unsigned short* dst = Wtf + f * 512 + l * 8;
#pragma unroll
    for (int j = 0; j < 8; ++j)
        dst[j] = f2bf(W[(kbase + j) * 64 + wcol] * scale);
}

// ---------------------------------------------------------------------------
// Kernel 2: QKV projection. 1 wave per block, 16 rows x 192 cols per wave.
// x fp32 converted to bf16 in-flight. Outputs: kbuf/qbuf bf16 [8192][64],
// vtb bf16 [B][64][T] (transposed for PV B-operand).
// ---------------------------------------------------------------------------
__global__ __launch_bounds__(64) void proj_kernel(const float* __restrict__ x,
                                                  const unsigned short* __restrict__ Wtf,
                                                  unsigned short* __restrict__ kbuf,
                                                  unsigned short* __restrict__ qbuf,
                                                  unsigned short* __restrict__ vtb) {
    int l = threadIdx.x, lm = l & 15, lg = l >> 4;
    int r0 = blockIdx.x * 16;
    f32x4 acc[12];
#pragma unroll
    for (int n = 0; n < 12; ++n) acc[n] = f32x4{0.f, 0.f, 0.f, 0.f};

    const float* xp = x + (r0 + lm) * C_ + lg * 8;
    const unsigned short* wp = Wtf + l * 8;

    for (int kk = 0; kk < 32; ++kk) {
        float4v a0 = *(const float4v*)(xp);
        float4v a1 = *(const float4v*)(xp + 4);
        xp += 32;
        short8 av;
#pragma unroll
        for (int j = 0; j < 4; ++j) {
            av[j]     = (short)f2bf(a0[j]);
            av[4 + j] = (short)f2bf(a1[j]);
        }
        bf16x8 af = __builtin_bit_cast(bf16x8, av);
#pragma unroll
        for (int n = 0; n < 12; ++n) {
            short8 bv = *(const short8*)(wp + n * 512);
            acc[n] = mfma16(af, __builtin_bit_cast(bf16x8, bv), acc[n]);
        }
        wp += 12 * 512;
    }

    int tg0 = r0 + lg * 4;              // global token of D-row i=0
    int b = tg0 >> 11, tt = tg0 & 2047;
#pragma unroll
    for (int n = 0; n < 12; ++n) {
        int col = n * 16 + lm;
        if (n < 4) {
#pragma unroll
            for (int i = 0; i < 4; ++i) kbuf[(tg0 + i) * H_ + col] = f2bf(acc[n][i]);
        } else if (n < 8) {
#pragma unroll
            for (int i = 0; i < 4; ++i) qbuf[(tg0 + i) * H_ + (col - 64)] = f2bf(acc[n][i]);
        } else {
            short4v pv;
#pragma unroll
            for (int i = 0; i < 4; ++i) pv[i] = (short)f2bf(acc[n][i]);
            *(short4v*)(vtb + (b * H_ + (col - 128)) * T_ + tt) = pv;
        }
    }
}

// ---------------------------------------------------------------------------
// Kernel 3: causal flash attention. Block = 16 Q-rows, 4 waves stripe KV tiles
// of 32 keys. Online softmax in-register; P repack via per-wave LDS; final
// cross-wave (m,l,O) merge through LDS. Q was pre-scaled by 1/32 via Wq.
// ---------------------------------------------------------------------------
__global__ __launch_bounds__(256) void attn_kernel(const unsigned short* __restrict__ kbuf,
                                                   const unsigned short* __restrict__ qbuf,
                                                   const unsigned short* __restrict__ vtb,
                                                   float* __restrict__ out) {
    int tid = threadIdx.x;
    int l = tid & 63, lm = l & 15, lg = l >> 4;
    int w = tid >> 6;                         // wave id 0..3
    int bid = blockIdx.x;
    int b = bid >> 7;
    int qt = 127 - (bid & 127);               // big-work blocks first
    int q0 = qt * 16;

    __shared__ alignas(16) unsigned short plds[4][16][48];
    __shared__ float olds[4][16][64];
    __shared__ float mlds[4][16];
    __shared__ float llds[4][16];

    // Q fragments (same 16 rows for all waves)
    bf16x8 qf[2];
#pragma unroll
    for (int kk = 0; kk < 2; ++kk)
        qf[kk] = __builtin_bit_cast(bf16x8,
            *(const short8*)(qbuf + (b * T_ + q0 + lm) * H_ + kk * 32 + lg * 8));

    f32x4 of[4];
#pragma unroll
    for (int nh = 0; nh < 4; ++nh) of[nh] = f32x4{0.f, 0.f, 0.f, 0.f};
    float mrun[4], lrun[4];
#pragma unroll
    for (int i = 0; i < 4; ++i) { mrun[i] = -1e30f; lrun[i] = 0.f; }

    int nj = q0 / 32 + 1;                     // tiles of 32 keys, causal bound

    for (int j = w; j < nj; j += 4) {
        f32x4 s[2];
        s[0] = f32x4{0.f, 0.f, 0.f, 0.f};
        s[1] = f32x4{0.f, 0.f, 0.f, 0.f};
#pragma unroll
        for (int kk = 0; kk < 2; ++kk) {
#pragma unroll
            for (int n = 0; n < 2; ++n) {
                bf16x8 kf = __builtin_bit_cast(bf16x8,
                    *(const short8*)(kbuf + (b * T_ + j * 32 + n * 16 + lm) * H_ + kk * 32 + lg * 8));
                s[n] = mfma16(qf[kk], kf, s[n]);
            }
        }
        if (j == nj - 1) {                    // only the diagonal tile needs masking
#pragma unroll
            for (int n = 0; n < 2; ++n) {
                int kc = j * 32 + n * 16 + lm;
#pragma unroll
                for (int i = 0; i < 4; ++i) {
                    int qr = q0 + lg * 4 + i;
                    if (kc > qr) s[n][i] = -1e30f;
                }
            }
        }
        float alpha[4];
#pragma unroll
        for (int i = 0; i < 4; ++i) {
            float pm = fmaxf(s[0][i], s[1][i]);
#pragma unroll
            for (int d = 1; d < 16; d <<= 1) pm = fmaxf(pm, __shfl_xor(pm, d, 64));
            float mn = fmaxf(mrun[i], pm);
            float al = __expf(mrun[i] - mn);
            float e0 = __expf(s[0][i] - mn);
            float e1 = __expf(s[1][i] - mn);
            float rs = e0 + e1;
#pragma unroll
            for (int d = 1; d < 16; d <<= 1) rs += __shfl_xor(rs, d, 64);
            lrun[i] = lrun[i] * al + rs;
            mrun[i] = mn;
            alpha[i] = al;
            s[0][i] = e0; s[1][i] = e1;
        }
#pragma unroll
        for (int nh = 0; nh < 4; ++nh)
#pragma unroll
            for (int i = 0; i < 4; ++i) of[nh][i] *= alpha[i];

        // P: D-layout -> A-layout via per-wave LDS (single wave: DS is in-order)
#pragma unroll
        for (int n = 0; n < 2; ++n)
#pragma unroll
            for (int i = 0; i < 4; ++i)
                plds[w][lg * 4 + i][n * 16 + lm] = f2bf(s[n][i]);
        bf16x8 pf = __builtin_bit_cast(bf16x8, *(const short8*)(&plds[w][lm][lg * 8]));
#pragma unroll
        for (int nh = 0; nh < 4; ++nh) {
            bf16x8 vf = __builtin_bit_cast(bf16x8,
                *(const short8*)(vtb + (b * H_ + nh * 16 + lm) * T_ + j * 32 + lg * 8));
            of[nh] = mfma16(pf, vf, of[nh]);
        }
    }

    // cross-wave merge
#pragma unroll
    for (int nh = 0; nh < 4; ++nh)
#pragma unroll
        for (int i = 0; i < 4; ++i)
            olds[w][lg * 4 + i][nh * 16 + lm] = of[nh][i];
    if (lm == 0) {
#pragma unroll
        for (int i = 0; i < 4; ++i) {
            mlds[w][lg * 4 + i] = mrun[i];
            llds[w][lg * 4 + i] = lrun[i];
        }
    }
    __syncthreads();

#pragma unroll
    for (int i = 0; i < 4; ++i) {
        int row = lg * 4 + i;
        float m0 = mlds[0][row], m1 = mlds[1][row], m2 = mlds[2][row], m3 = mlds[3][row];
        float M = fmaxf(fmaxf(m0, m1), fmaxf(m2, m3));
        float e0 = __expf(m0 - M), e1 = __expf(m1 - M);
        float e2 = __expf(m2 - M), e3 = __expf(m3 - M);
        float L = llds[0][row] * e0 + llds[1][row] * e1 + llds[2][row] * e2 + llds[3][row] * e3;
        int cc = w * 16 + lm;
        float o = olds[0][row][cc] * e0 + olds[1][row][cc] * e1 +
                  olds[2][row][cc] * e2 + olds[3][row][cc] * e3;
        out[(b * T_ + q0 + row) * H_ + cc] = o / L;
    }
}

extern "C" void kernel_launch(void* const* d_in, const int* in_sizes, int n_in,
                              void* d_out, int out_size, void* d_ws, size_t ws_size,
                              hipStream_t stream) {
    const float* x  = (const float*)d_in[0];
    const float* Wk = (const float*)d_in[1];
    const float* Wq = (const float*)d_in[2];
    const float* Wv = (const float*)d_in[3];
    float* out = (float*)d_out;

    unsigned short* ws   = (unsigned short*)d_ws;
    unsigned short* Wtf  = ws;                       // 384 frags * 512 = 196608
    unsigned short* kbuf = Wtf + 384 * 512;          // 8192*64
    unsigned short* qbuf = kbuf + M_ * H_;           // 8192*64
    unsigned short* vtb  = qbuf + M_ * H_;           // 4*64*2048

    wconv_kernel<<<dim3(96), dim3(256), 0, stream>>>(Wk, Wq, Wv, Wtf);
    proj_kernel<<<dim3(M_ / 16), dim3(64), 0, stream>>>(x, Wtf, kbuf, qbuf, vtb);
    attn_kernel<<<dim3(B_ * (T_ / 16)), dim3(256), 0, stream>>>(kbuf, qbuf, vtb, out);
}

// Round 3
// 112.796 us; speedup vs baseline: 1.8588x; 1.8588x over previous
//
#include <hip/hip_runtime.h>

#define B_ 4
#define T_ 2048
#define C_ 1024
#define H_ 64
#define M_ (B_*T_)

typedef __bf16 bf16x8 __attribute__((ext_vector_type(8)));
typedef float f32x4 __attribute__((ext_vector_type(4)));
typedef short short8 __attribute__((ext_vector_type(8)));
typedef float float4v __attribute__((ext_vector_type(4)));

static __device__ __forceinline__ f32x4 mfma16(bf16x8 a, bf16x8 b, f32x4 c) {
    return __builtin_amdgcn_mfma_f32_16x16x32_bf16(a, b, c, 0, 0, 0);
}
static __device__ __forceinline__ unsigned short f2bfu(float f) {
    return __builtin_bit_cast(unsigned short, (__bf16)f);
}

// ---------------------------------------------------------------------------
// Kernel 1: repack Wk|Wq|Wv (fp32 [1024][64]) into bf16 MFMA B-fragment order.
// Wtf frag f = kk*12 + n (kk 0..31, n 0..11); lane l holds 8 elems:
// W[k=kk*32+(l>>4)*8+j][col n*16+(l&15)].  n 0-3: Wk, 4-7: Wq(*1/32), 8-11: Wv
// ---------------------------------------------------------------------------
__global__ __launch_bounds__(256) void wconv_kernel(const float* __restrict__ Wk,
                                                    const float* __restrict__ Wq,
                                                    const float* __restrict__ Wv,
                                                    unsigned short* __restrict__ Wtf) {
    int t = blockIdx.x * 256 + threadIdx.x;
    int f = t >> 6;
    int l = t & 63;
    int n = f % 12, kk = f / 12;
    int sel = n >> 2;
    int wcol = (n & 3) * 16 + (l & 15);
    int kbase = kk * 32 + (l >> 4) * 8;
    const float* W = (sel == 0) ? Wk : ((sel == 1) ? Wq : Wv);
    float scale = (sel == 1) ? 0.03125f : 1.0f;
    unsigned short* dst = Wtf + f * 512 + l * 8;
#pragma unroll
    for (int j = 0; j < 8; ++j)
        dst[j] = f2bfu(W[(kbase + j) * 64 + wcol] * scale);
}

// ---------------------------------------------------------------------------
// Kernel 2: QKV projection. 512 blocks x 256 thr (4 waves). Each wave: same 16
// rows, 3 of 12 col-tiles (x re-reads hit L1). Explicit next-iter prefetch.
// Outputs plain bf16 [8192][64] kbuf/qbuf/vbuf.
// ---------------------------------------------------------------------------
__global__ __launch_bounds__(256) void proj_kernel(const float* __restrict__ x,
                                                   const unsigned short* __restrict__ Wtf,
                                                   unsigned short* __restrict__ kbuf,
                                                   unsigned short* __restrict__ qbuf,
                                                   unsigned short* __restrict__ vbuf) {
    int tid = threadIdx.x;
    int l = tid & 63, lm = l & 15, lg = l >> 4;
    int w = tid >> 6;
    int r0 = blockIdx.x * 16;

    f32x4 acc[3];
#pragma unroll
    for (int nn = 0; nn < 3; ++nn) acc[nn] = f32x4{0.f, 0.f, 0.f, 0.f};

    const float* xp = x + (r0 + lm) * C_ + lg * 8;
    const unsigned short* wp = Wtf + (w * 3) * 512 + l * 8;

    float4v a0 = *(const float4v*)(xp);
    float4v a1 = *(const float4v*)(xp + 4);
    short8 b0 = *(const short8*)(wp);
    short8 b1 = *(const short8*)(wp + 512);
    short8 b2 = *(const short8*)(wp + 1024);

    for (int kk = 0; kk < 31; ++kk) {
        xp += 32; wp += 12 * 512;
        float4v na0 = *(const float4v*)(xp);
        float4v na1 = *(const float4v*)(xp + 4);
        short8 nb0 = *(const short8*)(wp);
        short8 nb1 = *(const short8*)(wp + 512);
        short8 nb2 = *(const short8*)(wp + 1024);
        bf16x8 af;
#pragma unroll
        for (int j = 0; j < 4; ++j) { af[j] = (__bf16)a0[j]; af[4 + j] = (__bf16)a1[j]; }
        acc[0] = mfma16(af, __builtin_bit_cast(bf16x8, b0), acc[0]);
        acc[1] = mfma16(af, __builtin_bit_cast(bf16x8, b1), acc[1]);
        acc[2] = mfma16(af, __builtin_bit_cast(bf16x8, b2), acc[2]);
        a0 = na0; a1 = na1; b0 = nb0; b1 = nb1; b2 = nb2;
    }
    {   // epilogue iteration kk = 31
        bf16x8 af;
#pragma unroll
        for (int j = 0; j < 4; ++j) { af[j] = (__bf16)a0[j]; af[4 + j] = (__bf16)a1[j]; }
        acc[0] = mfma16(af, __builtin_bit_cast(bf16x8, b0), acc[0]);
        acc[1] = mfma16(af, __builtin_bit_cast(bf16x8, b1), acc[1]);
        acc[2] = mfma16(af, __builtin_bit_cast(bf16x8, b2), acc[2]);
    }

    int tg0 = r0 + lg * 4;
#pragma unroll
    for (int nn = 0; nn < 3; ++nn) {
        int n = w * 3 + nn;
        int sel = n >> 2;
        int col = (n & 3) * 16 + lm;
        unsigned short* dst = (sel == 0) ? kbuf : ((sel == 1) ? qbuf : vbuf);
#pragma unroll
        for (int i = 0; i < 4; ++i)
            dst[(tg0 + i) * H_ + col] = f2bfu(acc[nn][i]);
    }
}

// ---------------------------------------------------------------------------
// Kernel 3: in-place re-layout of K and V into MFMA fragment order, one 32-key
// tile (4KB each) per block via LDS. After this:
//   kbuf: [b*64+jt][kk(2)][nn(2)][lane][8] : K[b, jt*32+nn*16+(l&15), kk*32+(l>>4)*8+j]
//   vbuf: [b*64+jt][nh(4)][lane][8]        : V[b, jt*32+(l>>4)*8+j, nh*16+(l&15)]
// ---------------------------------------------------------------------------
__global__ __launch_bounds__(256) void kvconv_kernel(unsigned short* __restrict__ kbuf,
                                                     unsigned short* __restrict__ vbuf) {
    __shared__ alignas(16) unsigned short klds[32][72];
    __shared__ alignas(16) unsigned short vlds[32][72];
    int tid = threadIdx.x;
    int bj = blockIdx.x;                       // b*64 + jt
    unsigned short* kt = kbuf + bj * 2048;
    unsigned short* vt = vbuf + bj * 2048;

    int row = tid >> 3, cq = (tid & 7) * 8;
    short8 kv = *(const short8*)(kt + row * 64 + cq);
    short8 vv = *(const short8*)(vt + row * 64 + cq);
    *(short8*)(&klds[row][cq]) = kv;
    *(short8*)(&vlds[row][cq]) = vv;
    __syncthreads();

    int l = tid & 63, lm = l & 15, lg = l >> 4;
    int f = tid >> 6;                          // 0..3
    int kk = f >> 1, nn = f & 1;
    short8 kf = *(const short8*)(&klds[nn * 16 + lm][kk * 32 + lg * 8]);
    short8 vf;
#pragma unroll
    for (int jj = 0; jj < 8; ++jj)
        vf[jj] = (short)vlds[lg * 8 + jj][f * 16 + lm];

    *(short8*)(kt + f * 512 + l * 8) = kf;
    *(short8*)(vt + f * 512 + l * 8) = vf;
}

// ---------------------------------------------------------------------------
// Kernel 4: causal flash attention. Block = 16 Q-rows, 4 waves stripe 64-key
// tiles. All K/V loads are coalesced fragments. XCD swizzle: batch b pinned to
// XCD pair {2b,2b+1}, parity-interleaved q-tiles for balance.
// ---------------------------------------------------------------------------
__global__ __launch_bounds__(256) void attn_kernel(const unsigned short* __restrict__ kbuf,
                                                   const unsigned short* __restrict__ qbuf,
                                                   const unsigned short* __restrict__ vbuf,
                                                   float* __restrict__ out) {
    int tid = threadIdx.x;
    int l = tid & 63, lm = l & 15, lg = l >> 4;
    int w = tid >> 6;
    int bid = blockIdx.x;
    int xcd = bid & 7, ii = bid >> 3;
    int b = xcd >> 1;
    int qtl = ii * 2 + (xcd & 1);              // 0..127, big-work first
    int q0 = (127 - qtl) * 16;

    __shared__ alignas(16) unsigned short plds[4][16][72];
    __shared__ float olds[4][16][64];
    __shared__ float mlds[4][16];
    __shared__ float llds[4][16];

    bf16x8 qf[2];
#pragma unroll
    for (int kk = 0; kk < 2; ++kk)
        qf[kk] = __builtin_bit_cast(bf16x8,
            *(const short8*)(qbuf + (b * T_ + q0 + lm) * H_ + kk * 32 + lg * 8));

    f32x4 of[4];
#pragma unroll
    for (int nh = 0; nh < 4; ++nh) of[nh] = f32x4{0.f, 0.f, 0.f, 0.f};
    float mrun[4], lrun[4];
#pragma unroll
    for (int i = 0; i < 4; ++i) { mrun[i] = -1e30f; lrun[i] = 0.f; }

    int nj = q0 / 64 + 1;                      // 64-key tiles, causal bound

    for (int J = w; J < nj; J += 4) {
        f32x4 s[4];
#pragma unroll
        for (int n = 0; n < 4; ++n) s[n] = f32x4{0.f, 0.f, 0.f, 0.f};
#pragma unroll
        for (int kk = 0; kk < 2; ++kk) {
#pragma unroll
            for (int n = 0; n < 4; ++n) {
                const unsigned short* kp = kbuf +
                    (((b * 64 + 2 * J + (n >> 1)) * 2 + kk) * 2 + (n & 1)) * 512 + l * 8;
                s[n] = mfma16(qf[kk], __builtin_bit_cast(bf16x8, *(const short8*)kp), s[n]);
            }
        }
        if (J == nj - 1) {
#pragma unroll
            for (int n = 0; n < 4; ++n) {
                int kc = J * 64 + n * 16 + lm;
#pragma unroll
                for (int i = 0; i < 4; ++i) {
                    int qr = q0 + lg * 4 + i;
                    if (kc > qr) s[n][i] = -1e30f;
                }
            }
        }
        float alpha[4];
#pragma unroll
        for (int i = 0; i < 4; ++i) {
            float pm = fmaxf(fmaxf(s[0][i], s[1][i]), fmaxf(s[2][i], s[3][i]));
#pragma unroll
            for (int d = 1; d < 16; d <<= 1) pm = fmaxf(pm, __shfl_xor(pm, d, 64));
            float mn = fmaxf(mrun[i], pm);
            float al = __expf(mrun[i] - mn);
            float rs = 0.f;
#pragma unroll
            for (int n = 0; n < 4; ++n) {
                float e = __expf(s[n][i] - mn);
                s[n][i] = e; rs += e;
            }
#pragma unroll
            for (int d = 1; d < 16; d <<= 1) rs += __shfl_xor(rs, d, 64);
            lrun[i] = lrun[i] * al + rs;
            mrun[i] = mn;
            alpha[i] = al;
        }
#pragma unroll
        for (int nh = 0; nh < 4; ++nh)
#pragma unroll
            for (int i = 0; i < 4; ++i) of[nh][i] *= alpha[i];

        // P: D-layout -> A-layout via per-wave LDS (same-wave DS is in-order)
#pragma unroll
        for (int n = 0; n < 4; ++n)
#pragma unroll
            for (int i = 0; i < 4; ++i)
                plds[w][lg * 4 + i][n * 16 + lm] = f2bfu(s[n][i]);
        bf16x8 pf[2];
#pragma unroll
        for (int ks = 0; ks < 2; ++ks)
            pf[ks] = __builtin_bit_cast(bf16x8,
                *(const short8*)(&plds[w][lm][ks * 32 + lg * 8]));
#pragma unroll
        for (int nh = 0; nh < 4; ++nh) {
#pragma unroll
            for (int ks = 0; ks < 2; ++ks) {
                const unsigned short* vp = vbuf +
                    ((b * 64 + 2 * J + ks) * 4 + nh) * 512 + l * 8;
                of[nh] = mfma16(pf[ks], __builtin_bit_cast(bf16x8, *(const short8*)vp), of[nh]);
            }
        }
    }

    // cross-wave merge
#pragma unroll
    for (int nh = 0; nh < 4; ++nh)
#pragma unroll
        for (int i = 0; i < 4; ++i)
            olds[w][lg * 4 + i][nh * 16 + lm] = of[nh][i];
    if (lm == 0) {
#pragma unroll
        for (int i = 0; i < 4; ++i) {
            mlds[w][lg * 4 + i] = mrun[i];
            llds[w][lg * 4 + i] = lrun[i];
        }
    }
    __syncthreads();

#pragma unroll
    for (int i = 0; i < 4; ++i) {
        int row = lg * 4 + i;
        float m0 = mlds[0][row], m1 = mlds[1][row], m2 = mlds[2][row], m3 = mlds[3][row];
        float M = fmaxf(fmaxf(m0, m1), fmaxf(m2, m3));
        float e0 = __expf(m0 - M), e1 = __expf(m1 - M);
        float e2 = __expf(m2 - M), e3 = __expf(m3 - M);
        float L = llds[0][row] * e0 + llds[1][row] * e1 + llds[2][row] * e2 + llds[3][row] * e3;
        int cc = w * 16 + lm;
        float o = olds[0][row][cc] * e0 + olds[1][row][cc] * e1 +
                  olds[2][row][cc] * e2 + olds[3][row][cc] * e3;
        out[(b * T_ + q0 + row) * H_ + cc] = o / L;
    }
}

extern "C" void kernel_launch(void* const* d_in, const int* in_sizes, int n_in,
                              void* d_out, int out_size, void* d_ws, size_t ws_size,
                              hipStream_t stream) {
    const float* x  = (const float*)d_in[0];
    const float* Wk = (const float*)d_in[1];
    const float* Wq = (const float*)d_in[2];
    const float* Wv = (const float*)d_in[3];
    float* out = (float*)d_out;

    unsigned short* ws   = (unsigned short*)d_ws;
    unsigned short* Wtf  = ws;                       // 384*512 shorts
    unsigned short* kbuf = Wtf + 384 * 512;          // 8192*64
    unsigned short* qbuf = kbuf + M_ * H_;           // 8192*64
    unsigned short* vbuf = qbuf + M_ * H_;           // 8192*64

    wconv_kernel<<<dim3(96), dim3(256), 0, stream>>>(Wk, Wq, Wv, Wtf);
    proj_kernel<<<dim3(M_ / 16), dim3(256), 0, stream>>>(x, Wtf, kbuf, qbuf, vbuf);
    kvconv_kernel<<<dim3(B_ * 64), dim3(256), 0, stream>>>(kbuf, vbuf);
    attn_kernel<<<dim3(B_ * (T_ / 16)), dim3(256), 0, stream>>>(kbuf, qbuf, vbuf, out);
}

// Round 4
// 106.938 us; speedup vs baseline: 1.9606x; 1.0548x over previous
//
#include <hip/hip_runtime.h>

#define B_ 4
#define T_ 2048
#define C_ 1024
#define H_ 64
#define M_ (B_*T_)

typedef __bf16 bf16x8 __attribute__((ext_vector_type(8)));
typedef float f32x4 __attribute__((ext_vector_type(4)));
typedef short short8 __attribute__((ext_vector_type(8)));
typedef short short4v __attribute__((ext_vector_type(4)));
typedef float float4v __attribute__((ext_vector_type(4)));

static __device__ __forceinline__ f32x4 mfma16(bf16x8 a, bf16x8 b, f32x4 c) {
    return __builtin_amdgcn_mfma_f32_16x16x32_bf16(a, b, c, 0, 0, 0);
}
static __device__ __forceinline__ unsigned short f2bfu(float f) {
    return __builtin_bit_cast(unsigned short, (__bf16)f);
}

// ---------------------------------------------------------------------------
// Kernel 1: repack Wk|Wq|Wv (fp32 [1024][64]) into bf16 MFMA B-fragment order.
// Wtf frag f = kk*12 + n (kk 0..31, n 0..11); lane l holds 8 elems:
// W[k=kk*32+(l>>4)*8+j][col n*16+(l&15)].  n 0-3: Wk, 4-7: Wq(*1/32), 8-11: Wv
// ---------------------------------------------------------------------------
__global__ __launch_bounds__(256) void wconv_kernel(const float* __restrict__ Wk,
                                                    const float* __restrict__ Wq,
                                                    const float* __restrict__ Wv,
                                                    unsigned short* __restrict__ Wtf) {
    int t = blockIdx.x * 256 + threadIdx.x;
    int f = t >> 6;
    int l = t & 63;
    int n = f % 12, kk = f / 12;
    int sel = n >> 2;
    int wcol = (n & 3) * 16 + (l & 15);
    int kbase = kk * 32 + (l >> 4) * 8;
    const float* W = (sel == 0) ? Wk : ((sel == 1) ? Wq : Wv);
    float scale = (sel == 1) ? 0.03125f : 1.0f;
    unsigned short* dst = Wtf + f * 512 + l * 8;
#pragma unroll
    for (int j = 0; j < 8; ++j)
        dst[j] = f2bfu(W[(kbase + j) * 64 + wcol] * scale);
}

// ---------------------------------------------------------------------------
// Kernel 2: QKV projection. 512 blocks x 256 thr (4 waves). Each wave: same 16
// rows, 3 of 12 col-tiles (x re-reads hit L1). Explicit next-iter prefetch.
// ---------------------------------------------------------------------------
__global__ __launch_bounds__(256) void proj_kernel(const float* __restrict__ x,
                                                   const unsigned short* __restrict__ Wtf,
                                                   unsigned short* __restrict__ kbuf,
                                                   unsigned short* __restrict__ qbuf,
                                                   unsigned short* __restrict__ vbuf) {
    int tid = threadIdx.x;
    int l = tid & 63, lm = l & 15, lg = l >> 4;
    int w = tid >> 6;
    int r0 = blockIdx.x * 16;

    f32x4 acc[3];
#pragma unroll
    for (int nn = 0; nn < 3; ++nn) acc[nn] = f32x4{0.f, 0.f, 0.f, 0.f};

    const float* xp = x + (r0 + lm) * C_ + lg * 8;
    const unsigned short* wp = Wtf + (w * 3) * 512 + l * 8;

    float4v a0 = *(const float4v*)(xp);
    float4v a1 = *(const float4v*)(xp + 4);
    short8 b0 = *(const short8*)(wp);
    short8 b1 = *(const short8*)(wp + 512);
    short8 b2 = *(const short8*)(wp + 1024);

    for (int kk = 0; kk < 31; ++kk) {
        xp += 32; wp += 12 * 512;
        float4v na0 = *(const float4v*)(xp);
        float4v na1 = *(const float4v*)(xp + 4);
        short8 nb0 = *(const short8*)(wp);
        short8 nb1 = *(const short8*)(wp + 512);
        short8 nb2 = *(const short8*)(wp + 1024);
        bf16x8 af;
#pragma unroll
        for (int j = 0; j < 4; ++j) { af[j] = (__bf16)a0[j]; af[4 + j] = (__bf16)a1[j]; }
        acc[0] = mfma16(af, __builtin_bit_cast(bf16x8, b0), acc[0]);
        acc[1] = mfma16(af, __builtin_bit_cast(bf16x8, b1), acc[1]);
        acc[2] = mfma16(af, __builtin_bit_cast(bf16x8, b2), acc[2]);
        a0 = na0; a1 = na1; b0 = nb0; b1 = nb1; b2 = nb2;
    }
    {   // epilogue iteration kk = 31
        bf16x8 af;
#pragma unroll
        for (int j = 0; j < 4; ++j) { af[j] = (__bf16)a0[j]; af[4 + j] = (__bf16)a1[j]; }
        acc[0] = mfma16(af, __builtin_bit_cast(bf16x8, b0), acc[0]);
        acc[1] = mfma16(af, __builtin_bit_cast(bf16x8, b1), acc[1]);
        acc[2] = mfma16(af, __builtin_bit_cast(bf16x8, b2), acc[2]);
    }

    int tg0 = r0 + lg * 4;
#pragma unroll
    for (int nn = 0; nn < 3; ++nn) {
        int n = w * 3 + nn;
        int sel = n >> 2;
        int col = (n & 3) * 16 + lm;
        unsigned short* dst = (sel == 0) ? kbuf : ((sel == 1) ? qbuf : vbuf);
#pragma unroll
        for (int i = 0; i < 4; ++i)
            dst[(tg0 + i) * H_ + col] = f2bfu(acc[nn][i]);
    }
}

// ---------------------------------------------------------------------------
// Kernel 3: in-place re-layout of K and V into MFMA fragment order (32-key
// tiles via LDS).
//   kbuf: [b*64+jt][kk(2)][nn(2)][lane][8] : K[b, jt*32+nn*16+(l&15), kk*32+(l>>4)*8+j]
//   vbuf: [b*64+jt][nh(4)][lane][8]        : V[b, jt*32+(l>>4)*8+j, nh*16+(l&15)]
// ---------------------------------------------------------------------------
__global__ __launch_bounds__(256) void kvconv_kernel(unsigned short* __restrict__ kbuf,
                                                     unsigned short* __restrict__ vbuf) {
    __shared__ alignas(16) unsigned short klds[32][72];
    __shared__ alignas(16) unsigned short vlds[32][72];
    int tid = threadIdx.x;
    int bj = blockIdx.x;                       // b*64 + jt
    unsigned short* kt = kbuf + bj * 2048;
    unsigned short* vt = vbuf + bj * 2048;

    int row = tid >> 3, cq = (tid & 7) * 8;
    short8 kv = *(const short8*)(kt + row * 64 + cq);
    short8 vv = *(const short8*)(vt + row * 64 + cq);
    *(short8*)(&klds[row][cq]) = kv;
    *(short8*)(&vlds[row][cq]) = vv;
    __syncthreads();

    int l = tid & 63, lm = l & 15, lg = l >> 4;
    int f = tid >> 6;                          // 0..3
    int kk = f >> 1, nn = f & 1;
    short8 kf = *(const short8*)(&klds[nn * 16 + lm][kk * 32 + lg * 8]);
    short8 vf;
#pragma unroll
    for (int jj = 0; jj < 8; ++jj)
        vf[jj] = (short)vlds[lg * 8 + jj][f * 16 + lm];

    *(short8*)(kt + f * 512 + l * 8) = kf;
    *(short8*)(vt + f * 512 + l * 8) = vf;
}

// ---------------------------------------------------------------------------
// Kernel 4: causal flash attention, SWAPPED QK^T (S = mfma(K,Q) so each lane
// owns one q-row: q = q0 + (l&15); 16 key-scores per 64-key tile). 8 waves
// stripe KV tiles. Row softmax = 15-op tree + 2 shuffles. P repack via LDS
// (b64 writes / b128 reads, same-wave). Q pre-scaled by 1/32 via Wq.
// ---------------------------------------------------------------------------
__global__ __launch_bounds__(512) void attn_kernel(const unsigned short* __restrict__ kbuf,
                                                   const unsigned short* __restrict__ qbuf,
                                                   const unsigned short* __restrict__ vbuf,
                                                   float* __restrict__ out) {
    int tid = threadIdx.x;
    int l = tid & 63, lm = l & 15, lg = l >> 4;
    int w = tid >> 6;                          // wave 0..7
    int bid = blockIdx.x;
    int xcd = bid & 7, ii = bid >> 3;
    int b = xcd >> 1;
    int qtl = ii * 2 + (xcd & 1);              // 0..127
    int q0 = (127 - qtl) * 16;                 // big-work blocks dispatched first

    __shared__ alignas(16) unsigned short plds[8][16][72];
    __shared__ float olds[8][16][64];
    __shared__ float mlds[8][16];
    __shared__ float llds[8][16];

    bf16x8 qf[2];                              // B-operand: Q[q0+lm][kk*32+lg*8+j]
#pragma unroll
    for (int kk = 0; kk < 2; ++kk)
        qf[kk] = __builtin_bit_cast(bf16x8,
            *(const short8*)(qbuf + (b * T_ + q0 + lm) * H_ + kk * 32 + lg * 8));

    f32x4 of[4];                               // of[nh][i] = O[q0+lg*4+i][nh*16+lm]
#pragma unroll
    for (int nh = 0; nh < 4; ++nh) of[nh] = f32x4{0.f, 0.f, 0.f, 0.f};
    float mrun = -1e30f, lrun = 0.f;           // per q-row = lm (uniform across lg)

    int nj = q0 / 64 + 1;

    for (int J = w; J < nj; J += 8) {
        f32x4 s[4];                            // s[n][i] = S[key J*64+(n>>1)*32+(n&1)*16+lg*4+i][q0+lm]
#pragma unroll
        for (int n = 0; n < 4; ++n) s[n] = f32x4{0.f, 0.f, 0.f, 0.f};
#pragma unroll
        for (int kk = 0; kk < 2; ++kk) {
#pragma unroll
            for (int n = 0; n < 4; ++n) {
                const unsigned short* kp = kbuf +
                    (((b * 64 + 2 * J + (n >> 1)) * 2 + kk) * 2 + (n & 1)) * 512 + l * 8;
                s[n] = mfma16(__builtin_bit_cast(bf16x8, *(const short8*)kp), qf[kk], s[n]);
            }
        }
        if (J == nj - 1) {                     // diagonal tile: mask key > q
            int qr = q0 + lm;
#pragma unroll
            for (int n = 0; n < 4; ++n) {
                int kc0 = J * 64 + (n >> 1) * 32 + (n & 1) * 16 + lg * 4;
#pragma unroll
                for (int i = 0; i < 4; ++i)
                    if (kc0 + i > qr) s[n][i] = -1e30f;
            }
        }
        // row-max: in-register tree (16 vals) + 2 shuffles across lg groups
        float pm0 = fmaxf(fmaxf(s[0][0], s[0][1]), fmaxf(s[0][2], s[0][3]));
        float pm1 = fmaxf(fmaxf(s[1][0], s[1][1]), fmaxf(s[1][2], s[1][3]));
        float pm2 = fmaxf(fmaxf(s[2][0], s[2][1]), fmaxf(s[2][2], s[2][3]));
        float pm3 = fmaxf(fmaxf(s[3][0], s[3][1]), fmaxf(s[3][2], s[3][3]));
        float pm = fmaxf(fmaxf(pm0, pm1), fmaxf(pm2, pm3));
        pm = fmaxf(pm, __shfl_xor(pm, 16, 64));
        pm = fmaxf(pm, __shfl_xor(pm, 32, 64));
        float mn = fmaxf(mrun, pm);
        float al = __expf(mrun - mn);
        float rsn[4];
#pragma unroll
        for (int n = 0; n < 4; ++n) {
            float e0 = __expf(s[n][0] - mn), e1 = __expf(s[n][1] - mn);
            float e2 = __expf(s[n][2] - mn), e3 = __expf(s[n][3] - mn);
            s[n][0] = e0; s[n][1] = e1; s[n][2] = e2; s[n][3] = e3;
            rsn[n] = (e0 + e1) + (e2 + e3);
        }
        float rs = (rsn[0] + rsn[1]) + (rsn[2] + rsn[3]);
        rs += __shfl_xor(rs, 16, 64);
        rs += __shfl_xor(rs, 32, 64);
        lrun = lrun * al + rs;
        mrun = mn;
        // alpha for D-rows (q = q0+lg*4+i) lives in lane lg*4+i (its lm matches)
        float alv[4];
#pragma unroll
        for (int i = 0; i < 4; ++i) alv[i] = __shfl(al, lg * 4 + i, 64);
#pragma unroll
        for (int nh = 0; nh < 4; ++nh)
#pragma unroll
            for (int i = 0; i < 4; ++i) of[nh][i] *= alv[i];

        // P repack: write P[q=lm][key] as short4 runs, read A-frag b128
#pragma unroll
        for (int n = 0; n < 4; ++n) {
            short4v pv;
#pragma unroll
            for (int i = 0; i < 4; ++i) pv[i] = (short)f2bfu(s[n][i]);
            *(short4v*)(&plds[w][lm][(n >> 1) * 32 + (n & 1) * 16 + lg * 4]) = pv;
        }
        bf16x8 pf[2];
#pragma unroll
        for (int ks = 0; ks < 2; ++ks)
            pf[ks] = __builtin_bit_cast(bf16x8,
                *(const short8*)(&plds[w][lm][ks * 32 + lg * 8]));
#pragma unroll
        for (int nh = 0; nh < 4; ++nh) {
#pragma unroll
            for (int ks = 0; ks < 2; ++ks) {
                const unsigned short* vp = vbuf +
                    ((b * 64 + 2 * J + ks) * 4 + nh) * 512 + l * 8;
                of[nh] = mfma16(pf[ks], __builtin_bit_cast(bf16x8, *(const short8*)vp), of[nh]);
            }
        }
    }

    // stash per-wave state
#pragma unroll
    for (int nh = 0; nh < 4; ++nh)
#pragma unroll
        for (int i = 0; i < 4; ++i)
            olds[w][lg * 4 + i][nh * 16 + lm] = of[nh][i];
    if (l < 16) {
        mlds[w][l] = mrun;
        llds[w][l] = lrun;
    }
    __syncthreads();

    // cross-wave merge: 512 threads cover 16x64 outputs (2 each)
    int row = tid >> 5;
    int c0 = tid & 31;
    float mw[8];
#pragma unroll
    for (int u = 0; u < 8; ++u) mw[u] = mlds[u][row];
    float M = fmaxf(fmaxf(fmaxf(mw[0], mw[1]), fmaxf(mw[2], mw[3])),
                    fmaxf(fmaxf(mw[4], mw[5]), fmaxf(mw[6], mw[7])));
    float ew[8];
    float L = 0.f;
#pragma unroll
    for (int u = 0; u < 8; ++u) { ew[u] = __expf(mw[u] - M); L += llds[u][row] * ew[u]; }
    float invL = 1.0f / L;
#pragma unroll
    for (int h = 0; h < 2; ++h) {
        int col = c0 + h * 32;
        float o = 0.f;
#pragma unroll
        for (int u = 0; u < 8; ++u) o += olds[u][row][col] * ew[u];
        out[(b * T_ + q0 + row) * H_ + col] = o * invL;
    }
}

extern "C" void kernel_launch(void* const* d_in, const int* in_sizes, int n_in,
                              void* d_out, int out_size, void* d_ws, size_t ws_size,
                              hipStream_t stream) {
    const float* x  = (const float*)d_in[0];
    const float* Wk = (const float*)d_in[1];
    const float* Wq = (const float*)d_in[2];
    const float* Wv = (const float*)d_in[3];
    float* out = (float*)d_out;

    unsigned short* ws   = (unsigned short*)d_ws;
    unsigned short* Wtf  = ws;                       // 384*512 shorts
    unsigned short* kbuf = Wtf + 384 * 512;          // 8192*64
    unsigned short* qbuf = kbuf + M_ * H_;           // 8192*64
    unsigned short* vbuf = qbuf + M_ * H_;           // 8192*64

    wconv_kernel<<<dim3(96), dim3(256), 0, stream>>>(Wk, Wq, Wv, Wtf);
    proj_kernel<<<dim3(M_ / 16), dim3(256), 0, stream>>>(x, Wtf, kbuf, qbuf, vbuf);
    kvconv_kernel<<<dim3(B_ * 64), dim3(256), 0, stream>>>(kbuf, vbuf);
    attn_kernel<<<dim3(B_ * (T_ / 16)), dim3(512), 0, stream>>>(kbuf, qbuf, vbuf, out);
}